// Round 8
// baseline (69.308 us; speedup 1.0000x reference)
//
#include <hip/hip_runtime.h>
#include <stdint.h>

#define B_N    16384
#define F_N    512
#define NPAIR  128            // 256 steps (1 pad + 255 sites) fused into 128 pairs per side

typedef float    f32x4  __attribute__((ext_vector_type(4)));
typedef short    s16x8  __attribute__((ext_vector_type(8)));
typedef int      i32x4  __attribute__((ext_vector_type(4)));
typedef unsigned u32x2  __attribute__((ext_vector_type(2)));

// ws layout (shorts): left pair-frags [0,262144), right [262144,524288),
// M (256 f32) at short 524288, c0 at short 524800.
// per pair-side: 2048 shorts = [A1hi(512)|A1lo(512)|A2hi(512)|A2lo(512)]
#define WS_SIDE_STRIDE 262144
#define WS_BYTES_NEEDED ((524800 + 2) * 2)

// pack 4 floats -> 2 packed-bf16 hi words + 2 lo words (trunc split)
static __device__ __forceinline__ void split4(const float* f, unsigned* ph, unsigned* pl) {
#pragma unroll
  for (int j = 0; j < 2; ++j) {
    float f0 = f[2*j], f1 = f[2*j+1];
    unsigned u0 = __float_as_uint(f0), u1 = __float_as_uint(f1);
    ph[j] = __builtin_amdgcn_perm(u1, u0, 0x07060302u);
    float l0 = f0 - __uint_as_float(u0 & 0xffff0000u);
    float l1 = f1 - __uint_as_float(u1 & 0xffff0000u);
    pl[j] = __builtin_amdgcn_perm(__float_as_uint(l1), __float_as_uint(l0), 0x07060302u);
  }
}

// 8 floats -> 4 hi + 4 lo words (split4 consumes 4 floats / writes 2 words)
static __device__ __forceinline__ void split_pack8(const float* f, unsigned* ph, unsigned* pl) {
  split4(f,     ph,     pl);
  split4(f + 4, ph + 2, pl + 2);
}

// swap32: lo lanes -> (a_own, a_from_hi); hi lanes -> (b_from_lo, b_own)
static __device__ __forceinline__ void swap32p(unsigned a, unsigned b, unsigned &x, unsigned &y) {
#if __has_builtin(__builtin_amdgcn_permlane32_swap)
  u32x2 r = __builtin_amdgcn_permlane32_swap(a, b, false, false);
  x = (unsigned)r.x; y = (unsigned)r.y;
#else
  unsigned oa = (unsigned)__shfl_xor((int)a, 32, 64);
  unsigned ob = (unsigned)__shfl_xor((int)b, 32, 64);
  bool hi = (threadIdx.x & 32) != 0;
  x = hi ? ob : a;
  y = hi ? b  : oa;
#endif
}

static __device__ __forceinline__ s16x8 as_s16x8(const unsigned* p) {
  i32x4 v; v.x = (int)p[0]; v.y = (int)p[1]; v.z = (int)p[2]; v.w = (int)p[3];
  return __builtin_bit_cast(s16x8, v);
}

// tau: swap bits 2<->3 of a 4-bit row index
static __device__ __forceinline__ int tau(int m) {
  return (m & 3) | ((m & 4) << 1) | ((m & 8) >> 1);
}

// ---------------- prep: fuse site pairs, emit 16x16x32 K-stacked MFMA A-frags ----------
// (unchanged from round 6 — verified correct)
__global__ __launch_bounds__(256) void mps_prep(
    const float* __restrict__ W0, const float* __restrict__ W_left,
    const float* __restrict__ W_out, const float* __restrict__ W_right,
    const float* __restrict__ WN, const float* __restrict__ d1_w,
    const float* __restrict__ d1_b, const float* __restrict__ d2_w,
    const float* __restrict__ d2_b, unsigned short* __restrict__ ws)
{
  int bid = blockIdx.x;
  if (bid < 256) {
    int side = bid >> 7;
    int pair = bid & 127;
    __shared__ float Wa[512];    // [d*32 + p*16 + m]
    __shared__ float Wb[512];
    __shared__ float Af[1024];
    int t = threadIdx.x;
    bool pad_a = (pair == 0);
    const float* base_a = side ? (W_right + (size_t)(255 - 2*pair) * 512)
                               : (W_left  + (size_t)(2*pair - 1) * 512);
    const float* base_b = side ? (W_right + (size_t)(254 - 2*pair) * 512)
                               : (W_left  + (size_t)(2*pair) * 512);
#pragma unroll
    for (int e = t; e < 512; e += 256) {
      float va;
      if (pad_a) { int d = e >> 5, p = (e >> 4) & 1, m = e & 15; va = (p == 0 && d == m) ? 1.f : 0.f; }
      else va = base_a[e];
      Wa[e] = va;
      Wb[e] = base_b[e];
    }
    __syncthreads();
#pragma unroll
    for (int ei = t; ei < 1024; ei += 256) {
      int amat = ei >> 9;
      int rem  = ei & 511;
      int m32  = rem >> 4;
      int k    = rem & 15;
      int pa   = m32 >> 4;
      int m    = tau(m32 & 15);
      float acc = 0.f;
      if (side == 0) {
#pragma unroll
        for (int j = 0; j < 16; ++j) acc += Wa[k*32 + pa*16 + j] * Wb[j*32 + amat*16 + m];
      } else {
#pragma unroll
        for (int j = 0; j < 16; ++j) acc += Wb[m*32 + amat*16 + j] * Wa[j*32 + pa*16 + k];
      }
      Af[ei] = acc;
    }
    __syncthreads();
    {
      int f = t >> 6, l = t & 63;          // f: 0=A1hi 1=A1lo 2=A2hi 3=A2lo
      int amat = f >> 1, lo = f & 1;
      int m = l & 15, kb = (l >> 4) * 8;
      s16x8 v8;
#pragma unroll
      for (int i = 0; i < 8; ++i) {
        int k = kb + i;
        float w = Af[amat*512 + ((k >> 4)*16 + m)*16 + (k & 15)];
        unsigned u = __float_as_uint(w);
        unsigned short h = (unsigned short)(u >> 16);
        if (lo) {
          float rl = w - __uint_as_float((unsigned)h << 16);
          h = (unsigned short)(__float_as_uint(rl) >> 16);
        }
        v8[i] = (short)h;
      }
      *reinterpret_cast<s16x8*>(ws + (size_t)side * WS_SIDE_STRIDE
                                   + (size_t)pair * 2048 + f * 512 + l * 8) = v8;
    }
  } else {
    int t = threadIdx.x;
    int d = t >> 4, e = t & 15;
    float acc = 0.f;
#pragma unroll
    for (int o = 0; o < 8; ++o) {
      float wef = 0.f;
      for (int hh = 0; hh < 24; ++hh) wef += d2_w[hh] * d1_w[hh*8 + o];
      acc += wef * W_out[d*128 + o*16 + e];
    }
    float* wf = reinterpret_cast<float*>(ws);
    wf[262144 + t] = acc;
    if (t == 0) {
      float c0 = d2_b[0];
      for (int hh = 0; hh < 24; ++hh) c0 += d2_w[hh] * d1_b[hh];
      wf[262400] = c0;
    }
  }
}

// ---------------- main: 512 blocks x 4 waves {L0,L1,R0,R1}, 16 samples/wave -----------
// Per-wave private LDS staging, 4-buffer rotation (kills the r7 WAR race), prefetch
// depth 3 with counted vmcnt(8), register double-buffer of A-frags (read 1 pair ahead).
__global__ __launch_bounds__(256, 2) void mps_main(
    const float* __restrict__ x, const float* __restrict__ W0,
    const float* __restrict__ WN, const unsigned short* __restrict__ ws,
    float* __restrict__ out)
{
  __shared__ __align__(16) unsigned short sbuf[4][4][4][64][8];  // [wave][buf][frag][lane][8] = 64 KiB
  __shared__ float fin[2][32][16];                               // 4 KiB

  const int tidx = threadIdx.x;
  const int wave = tidx >> 6;
  const int lane = tidx & 63;
  const int side = wave >> 1;
  const int q    = wave & 1;
  const int n    = lane & 15;         // sample column
  const int g    = lane >> 4;         // lane group (k-range 8g..8g+7)
  const int b    = blockIdx.x * 32 + q * 16 + n;
  const float* xrow = x + (size_t)b * F_N;
  const unsigned short* frag = ws + (size_t)side * WS_SIDE_STRIDE;
  const int rbase = ((g & 1) << 3) | ((g & 2) << 1);   // D natural-row base: 0,8,4,12

  // init B-operand for pair 0: vv = [v0 ; xa*v0]
  unsigned bw[4], bwl[4];
  {
    float xi0 = side ? xrow[F_N-1] : xrow[0];
    float f8[8];
#pragma unroll
    for (int i = 0; i < 8; ++i) {
      int k = g*8 + i;
      int j = k & 15;
      float a0 = side ? WN[j*2]   : W0[j];
      float a1 = side ? WN[j*2+1] : W0[16+j];
      float v0 = fmaf(xi0, a1, a0);
      f8[i] = (g >= 2) ? xi0 * v0 : v0;
    }
    split_pack8(f8, bw, bwl);
  }

  f32x4 Dz = {0.f, 0.f, 0.f, 0.f};

  auto stage = [&](int p) {                     // stage pair p into buf p&3 (own wave only)
    const unsigned short* gs = frag + (size_t)p * 2048;
#pragma unroll
    for (int fg = 0; fg < 4; ++fg) {
      __builtin_amdgcn_global_load_lds(
        (const __attribute__((address_space(1))) void*)(gs + fg*512 + lane*8),
        (__attribute__((address_space(3))) void*)(&sbuf[wave][p & 3][fg][0][0]),
        16, 0, 0);
    }
  };

  auto xp0 = [&](int c) { return xrow + (side ? (504 - 8*c) : (8*c)); };
  auto xp1 = [&](int c) { return xrow + (side ? (508 - 8*c) : (8*c + 4)); };

  float4 xc0 = *reinterpret_cast<const float4*>(xp0(0));
  float4 xc1 = *reinterpret_cast<const float4*>(xp1(0));

  stage(0);
  stage(1);
  stage(2);
  asm volatile("s_waitcnt vmcnt(8)" ::: "memory");   // pair 0 landed (1,2 in flight)

  // preload pair-0 frags into registers
  s16x8 f0a, f0b, f0c, f0d;
  {
    const unsigned short* lb = &sbuf[wave][0][0][0][0];
    f0a = *reinterpret_cast<const s16x8*>(lb + 0*512 + lane*8);
    f0b = *reinterpret_cast<const s16x8*>(lb + 1*512 + lane*8);
    f0c = *reinterpret_cast<const s16x8*>(lb + 2*512 + lane*8);
    f0d = *reinterpret_cast<const s16x8*>(lb + 3*512 + lane*8);
  }

  float st[4];
#pragma unroll 1
  for (int c = 0; c < 32; ++c) {
    float4 xn0 = xc0, xn1 = xc1;
    if (c + 1 < 32) {
      xn0 = *reinterpret_cast<const float4*>(xp0(c + 1));
      xn1 = *reinterpret_cast<const float4*>(xp1(c + 1));
    }
    float xa[5], xb[4];
    if (side == 0) {
      xa[0]=xc0.x; xa[1]=xc0.z; xa[2]=xc1.x; xa[3]=xc1.z; xa[4]=xn0.x;
      xb[0]=xc0.y; xb[1]=xc0.w; xb[2]=xc1.y; xb[3]=xc1.w;
    } else {
      xa[0]=xc1.w; xa[1]=xc1.y; xa[2]=xc0.w; xa[3]=xc0.y; xa[4]=xn1.w;
      xb[0]=xc1.z; xb[1]=xc1.x; xb[2]=xc0.z; xb[3]=xc0.x;
    }

#pragma unroll
    for (int pr = 0; pr < 4; ++pr) {
      const int p = c*4 + pr;
      // prefetch pair p+3 (writes buf (p-1)&3, whose reads drained one iter ago);
      // counted wait guarantees pair p+1's stage (issued 2-3 iters ago) has landed.
      if (p + 3 < NPAIR) {
        stage(p + 3);
        asm volatile("s_waitcnt vmcnt(8)" ::: "memory");
      } else if (p + 2 < NPAIR) {
        asm volatile("s_waitcnt vmcnt(4)" ::: "memory");
      } else {
        asm volatile("s_waitcnt vmcnt(0)" ::: "memory");
      }
      // ds_read pair p+1 frags (latency hides under pair-p compute)
      s16x8 n0 = f0a, n1 = f0b, n2 = f0c, n3 = f0d;
      if (p + 1 < NPAIR) {
        const unsigned short* lb = &sbuf[wave][(p + 1) & 3][0][0][0];
        n0 = *reinterpret_cast<const s16x8*>(lb + 0*512 + lane*8);
        n1 = *reinterpret_cast<const s16x8*>(lb + 1*512 + lane*8);
        n2 = *reinterpret_cast<const s16x8*>(lb + 2*512 + lane*8);
        n3 = *reinterpret_cast<const s16x8*>(lb + 3*512 + lane*8);
      }

      s16x8 Bh = as_s16x8(bw), Bl = as_s16x8(bwl);
      // two parallel 3-deep acc chains
      f32x4 D1 = __builtin_amdgcn_mfma_f32_16x16x32_bf16(f0a, Bh, Dz, 0, 0, 0);
      f32x4 D2 = __builtin_amdgcn_mfma_f32_16x16x32_bf16(f0c, Bh, Dz, 0, 0, 0);
      D1 = __builtin_amdgcn_mfma_f32_16x16x32_bf16(f0a, Bl, D1, 0, 0, 0);
      D2 = __builtin_amdgcn_mfma_f32_16x16x32_bf16(f0c, Bl, D2, 0, 0, 0);
      D1 = __builtin_amdgcn_mfma_f32_16x16x32_bf16(f0b, Bh, D1, 0, 0, 0);
      D2 = __builtin_amdgcn_mfma_f32_16x16x32_bf16(f0d, Bh, D2, 0, 0, 0);

#pragma unroll
      for (int r = 0; r < 4; ++r) st[r] = fmaf(xb[pr], D2[r], D1[r]);

      // build next B: split, then 2 swap32 per precision
      float xs[4];
#pragma unroll
      for (int r = 0; r < 4; ++r) xs[r] = xa[pr + 1] * st[r];
      unsigned vh2[2], vl2[2], xh2[2], xl2[2];
      split4(st, vh2, vl2);
      split4(xs, xh2, xl2);
      swap32p(vh2[0], xh2[0], bw[0], bw[2]);
      swap32p(vh2[1], xh2[1], bw[1], bw[3]);
      swap32p(vl2[0], xl2[0], bwl[0], bwl[2]);
      swap32p(vl2[1], xl2[1], bwl[1], bwl[3]);

      f0a = n0; f0b = n1; f0c = n2; f0d = n3;
    }
    xc0 = xn0; xc1 = xn1;
  }

  // final f32 state (natural rows rbase..rbase+3) -> LDS
#pragma unroll
  for (int r = 0; r < 4; ++r) fin[side][q*16 + n][rbase + r] = st[r];
  __syncthreads();

  // head: y = c0 + v^T M u, 8 threads per sample
  {
    int s = tidx >> 3, j = tidx & 7;
    const float* Mf = reinterpret_cast<const float*>(ws) + 262144;
    float c0 = reinterpret_cast<const float*>(ws)[262400];
    float acc = 0.f;
#pragma unroll
    for (int dd = 0; dd < 2; ++dd) {
      int d = j*2 + dd;
      float zd = 0.f;
#pragma unroll
      for (int e = 0; e < 16; ++e) zd = fmaf(Mf[d*16 + e], fin[1][s][e], zd);
      acc = fmaf(fin[0][s][d], zd, acc);
    }
    acc += __shfl_xor(acc, 1, 64);
    acc += __shfl_xor(acc, 2, 64);
    acc += __shfl_xor(acc, 4, 64);
    if (j == 0) out[blockIdx.x*32 + s] = acc + c0;
  }
}

extern "C" void kernel_launch(void* const* d_in, const int* in_sizes, int n_in,
                              void* d_out, int out_size, void* d_ws, size_t ws_size,
                              hipStream_t stream)
{
  const float* x       = (const float*)d_in[0];
  const float* W0      = (const float*)d_in[1];
  const float* W_left  = (const float*)d_in[2];
  const float* W_out   = (const float*)d_in[3];
  const float* W_right = (const float*)d_in[4];
  const float* WN      = (const float*)d_in[5];
  const float* d1_w    = (const float*)d_in[6];
  const float* d1_b    = (const float*)d_in[7];
  const float* d2_w    = (const float*)d_in[8];
  const float* d2_b    = (const float*)d_in[9];
  unsigned short* ws   = (unsigned short*)d_ws;
  float* out           = (float*)d_out;

  if (ws_size < (size_t)WS_BYTES_NEEDED) return;

  hipLaunchKernelGGL(mps_prep, dim3(257), dim3(256), 0, stream,
                     W0, W_left, W_out, W_right, WN, d1_w, d1_b, d2_w, d2_b, ws);
  hipLaunchKernelGGL(mps_main, dim3(B_N/32), dim3(256), 0, stream,
                     x, W0, WN, ws, out);
}

// Round 9
// 65.478 us; speedup vs baseline: 1.0585x; 1.0585x over previous
//
#include <hip/hip_runtime.h>
#include <stdint.h>

#define B_N    16384
#define F_N    512
#define NPAIR  128            // 256 steps (1 pad + 255 sites) fused into 128 pairs per side
#define CHUNKP 8              // pairs per staged chunk
#define NCHUNK (NPAIR/CHUNKP)

typedef float    f32x4  __attribute__((ext_vector_type(4)));
typedef short    s16x8  __attribute__((ext_vector_type(8)));
typedef int      i32x4  __attribute__((ext_vector_type(4)));
typedef unsigned u32x2  __attribute__((ext_vector_type(2)));

// ws layout (shorts): left pair-frags [0,262144), right [262144,524288),
// M (256 f32) at short 524288, c0 at short 524800.
// per pair-side: 2048 shorts = [A1hi(512)|A1lo(512)|A2hi(512)|A2lo(512)]
#define WS_SIDE_STRIDE 262144
#define WS_BYTES_NEEDED ((524800 + 2) * 2)

// pack 4 floats -> 2 packed-bf16 hi words + 2 lo words (trunc split)
static __device__ __forceinline__ void split4(const float* f, unsigned* ph, unsigned* pl) {
#pragma unroll
  for (int j = 0; j < 2; ++j) {
    float f0 = f[2*j], f1 = f[2*j+1];
    unsigned u0 = __float_as_uint(f0), u1 = __float_as_uint(f1);
    ph[j] = __builtin_amdgcn_perm(u1, u0, 0x07060302u);
    float l0 = f0 - __uint_as_float(u0 & 0xffff0000u);
    float l1 = f1 - __uint_as_float(u1 & 0xffff0000u);
    pl[j] = __builtin_amdgcn_perm(__float_as_uint(l1), __float_as_uint(l0), 0x07060302u);
  }
}

// 8 floats -> 4 hi + 4 lo words (split4 consumes 4 floats / writes 2 words)
static __device__ __forceinline__ void split_pack8(const float* f, unsigned* ph, unsigned* pl) {
  split4(f,     ph,     pl);
  split4(f + 4, ph + 2, pl + 2);
}

// swap32: lo lanes -> (a_own, a_from_hi); hi lanes -> (b_from_lo, b_own)
static __device__ __forceinline__ void swap32p(unsigned a, unsigned b, unsigned &x, unsigned &y) {
#if __has_builtin(__builtin_amdgcn_permlane32_swap)
  u32x2 r = __builtin_amdgcn_permlane32_swap(a, b, false, false);
  x = (unsigned)r.x; y = (unsigned)r.y;
#else
  unsigned oa = (unsigned)__shfl_xor((int)a, 32, 64);
  unsigned ob = (unsigned)__shfl_xor((int)b, 32, 64);
  bool hi = (threadIdx.x & 32) != 0;
  x = hi ? ob : a;
  y = hi ? b  : oa;
#endif
}

static __device__ __forceinline__ s16x8 as_s16x8(const unsigned* p) {
  i32x4 v; v.x = (int)p[0]; v.y = (int)p[1]; v.z = (int)p[2]; v.w = (int)p[3];
  return __builtin_bit_cast(s16x8, v);
}

// tau: swap bits 2<->3 of a 4-bit row index
static __device__ __forceinline__ int tau(int m) {
  return (m & 3) | ((m & 4) << 1) | ((m & 8) >> 1);
}

// ---------------- prep: fuse site pairs, emit 16x16x32 K-stacked MFMA A-frags ----------
// (unchanged — verified correct since round 6)
__global__ __launch_bounds__(256) void mps_prep(
    const float* __restrict__ W0, const float* __restrict__ W_left,
    const float* __restrict__ W_out, const float* __restrict__ W_right,
    const float* __restrict__ WN, const float* __restrict__ d1_w,
    const float* __restrict__ d1_b, const float* __restrict__ d2_w,
    const float* __restrict__ d2_b, unsigned short* __restrict__ ws)
{
  int bid = blockIdx.x;
  if (bid < 256) {
    int side = bid >> 7;
    int pair = bid & 127;
    __shared__ float Wa[512];    // [d*32 + p*16 + m]
    __shared__ float Wb[512];
    __shared__ float Af[1024];
    int t = threadIdx.x;
    bool pad_a = (pair == 0);
    const float* base_a = side ? (W_right + (size_t)(255 - 2*pair) * 512)
                               : (W_left  + (size_t)(2*pair - 1) * 512);
    const float* base_b = side ? (W_right + (size_t)(254 - 2*pair) * 512)
                               : (W_left  + (size_t)(2*pair) * 512);
#pragma unroll
    for (int e = t; e < 512; e += 256) {
      float va;
      if (pad_a) { int d = e >> 5, p = (e >> 4) & 1, m = e & 15; va = (p == 0 && d == m) ? 1.f : 0.f; }
      else va = base_a[e];
      Wa[e] = va;
      Wb[e] = base_b[e];
    }
    __syncthreads();
#pragma unroll
    for (int ei = t; ei < 1024; ei += 256) {
      int amat = ei >> 9;
      int rem  = ei & 511;
      int m32  = rem >> 4;
      int k    = rem & 15;
      int pa   = m32 >> 4;
      int m    = tau(m32 & 15);
      float acc = 0.f;
      if (side == 0) {
#pragma unroll
        for (int j = 0; j < 16; ++j) acc += Wa[k*32 + pa*16 + j] * Wb[j*32 + amat*16 + m];
      } else {
#pragma unroll
        for (int j = 0; j < 16; ++j) acc += Wb[m*32 + amat*16 + j] * Wa[j*32 + pa*16 + k];
      }
      Af[ei] = acc;
    }
    __syncthreads();
    {
      int f = t >> 6, l = t & 63;          // f: 0=A1hi 1=A1lo 2=A2hi 3=A2lo
      int amat = f >> 1, lo = f & 1;
      int m = l & 15, kb = (l >> 4) * 8;
      s16x8 v8;
#pragma unroll
      for (int i = 0; i < 8; ++i) {
        int k = kb + i;
        float w = Af[amat*512 + ((k >> 4)*16 + m)*16 + (k & 15)];
        unsigned u = __float_as_uint(w);
        unsigned short h = (unsigned short)(u >> 16);
        if (lo) {
          float rl = w - __uint_as_float((unsigned)h << 16);
          h = (unsigned short)(__float_as_uint(rl) >> 16);
        }
        v8[i] = (short)h;
      }
      *reinterpret_cast<s16x8*>(ws + (size_t)side * WS_SIDE_STRIDE
                                   + (size_t)pair * 2048 + f * 512 + l * 8) = v8;
    }
  } else {
    int t = threadIdx.x;
    int d = t >> 4, e = t & 15;
    float acc = 0.f;
#pragma unroll
    for (int o = 0; o < 8; ++o) {
      float wef = 0.f;
      for (int hh = 0; hh < 24; ++hh) wef += d2_w[hh] * d1_w[hh*8 + o];
      acc += wef * W_out[d*128 + o*16 + e];
    }
    float* wf = reinterpret_cast<float*>(ws);
    wf[262144 + t] = acc;
    if (t == 0) {
      float c0 = d2_b[0];
      for (int hh = 0; hh < 24; ++hh) c0 += d2_w[hh] * d1_b[hh];
      wf[262400] = c0;
    }
  }
}

// ---------------- main: 256 blocks x 8 waves {L,L,L,L,R,R,R,R}, 16 samples/wave --------
// All 8 waves cooperatively stage BOTH sides' chunk once per block (frag L2 traffic
// = 256 MB total, 1/4 of round 8). Double-buffered chunks of 8 pairs, one barrier each.
__global__ __launch_bounds__(512, 1) void mps_main(
    const float* __restrict__ x, const float* __restrict__ W0,
    const float* __restrict__ WN, const unsigned short* __restrict__ ws,
    float* __restrict__ out)
{
  __shared__ __align__(16) unsigned short sbuf[2][2][CHUNKP][4][64][8]; // 128 KiB
  __shared__ float fin[2][64][16];                                      // 8 KiB

  const int tidx = threadIdx.x;
  const int wave = tidx >> 6;
  const int lane = tidx & 63;
  const int side = wave >> 2;         // waves 0-3 left, 4-7 right
  const int q    = wave & 3;          // sample group
  const int n    = lane & 15;         // sample column
  const int g    = lane >> 4;         // lane group (k-range 8g..8g+7)
  const int b    = blockIdx.x * 64 + q * 16 + n;
  const float* xrow = x + (size_t)b * F_N;
  const int rbase = ((g & 1) << 3) | ((g & 2) << 1);   // D natural-row base: 0,8,4,12

  // init B-operand for pair 0: vv = [v0 ; xa*v0]
  unsigned bw[4], bwl[4];
  {
    float xi0 = side ? xrow[F_N-1] : xrow[0];
    float f8[8];
#pragma unroll
    for (int i = 0; i < 8; ++i) {
      int k = g*8 + i;
      int j = k & 15;
      float a0 = side ? WN[j*2]   : W0[j];
      float a1 = side ? WN[j*2+1] : W0[16+j];
      float v0 = fmaf(xi0, a1, a0);
      f8[i] = (g >= 2) ? xi0 * v0 : v0;
    }
    split_pack8(f8, bw, bwl);
  }

  f32x4 Dz = {0.f, 0.f, 0.f, 0.f};

  // cooperative stage: 64 segments of 1 KB (2 sides x 8 pairs x 4 frags), 8 per wave
  auto stage = [&](int chunk, int db) {
#pragma unroll
    for (int s2 = 0; s2 < 8; ++s2) {
      int seg = wave * 8 + s2;
      int ss  = seg >> 5;
      int rem = seg & 31;
      int pr  = rem >> 2, fg = rem & 3;
      const unsigned short* src = ws + (size_t)ss * WS_SIDE_STRIDE
                                + (size_t)(chunk * CHUNKP + pr) * 2048 + fg * 512 + lane * 8;
      __builtin_amdgcn_global_load_lds(
        (const __attribute__((address_space(1))) void*)src,
        (__attribute__((address_space(3))) void*)(&sbuf[ss][db][pr][fg][0][0]),
        16, 0, 0);
    }
  };

  auto xbase = [&](int c) { return xrow + (side ? (496 - 16*c) : (16*c)); };

  float4 xq0, xq1, xq2, xq3;
  {
    const float* xp = xbase(0);
    xq0 = *reinterpret_cast<const float4*>(xp);
    xq1 = *reinterpret_cast<const float4*>(xp + 4);
    xq2 = *reinterpret_cast<const float4*>(xp + 8);
    xq3 = *reinterpret_cast<const float4*>(xp + 12);
  }

  stage(0, 0);
  asm volatile("s_waitcnt vmcnt(0)" ::: "memory");
  __syncthreads();

  float st[4];
#pragma unroll 1
  for (int c = 0; c < NCHUNK; ++c) {
    float4 xn0 = xq0, xn1 = xq1, xn2 = xq2, xn3 = xq3;
    if (c + 1 < NCHUNK) {
      stage(c + 1, (c + 1) & 1);
      const float* xp = xbase(c + 1);
      xn0 = *reinterpret_cast<const float4*>(xp);
      xn1 = *reinterpret_cast<const float4*>(xp + 4);
      xn2 = *reinterpret_cast<const float4*>(xp + 8);
      xn3 = *reinterpret_cast<const float4*>(xp + 12);
    }
    const unsigned short* lb = &sbuf[side][c & 1][0][0][0][0];

    // x schedule for this chunk (elem i = xbase[i])
    float xa[9], xb[8];
    {
      float e0=xq0.x, e1=xq0.y, e2=xq0.z, e3=xq0.w, e4=xq1.x, e5=xq1.y, e6=xq1.z, e7=xq1.w;
      float e8=xq2.x, e9=xq2.y, e10=xq2.z, e11=xq2.w, e12=xq3.x, e13=xq3.y, e14=xq3.z, e15=xq3.w;
      if (side == 0) {
        xa[0]=e0;  xb[0]=e1;  xa[1]=e2;  xb[1]=e3;
        xa[2]=e4;  xb[2]=e5;  xa[3]=e6;  xb[3]=e7;
        xa[4]=e8;  xb[4]=e9;  xa[5]=e10; xb[5]=e11;
        xa[6]=e12; xb[6]=e13; xa[7]=e14; xb[7]=e15;
        xa[8]=xn0.x;
      } else {
        xa[0]=e15; xb[0]=e14; xa[1]=e13; xb[1]=e12;
        xa[2]=e11; xb[2]=e10; xa[3]=e9;  xb[3]=e8;
        xa[4]=e7;  xb[4]=e6;  xa[5]=e5;  xb[5]=e4;
        xa[6]=e3;  xb[6]=e2;  xa[7]=e1;  xb[7]=e0;
        xa[8]=xn3.w;
      }
    }

#pragma unroll
    for (int pr = 0; pr < CHUNKP; ++pr) {
      s16x8 a1h = *reinterpret_cast<const s16x8*>(lb + pr*2048 + 0*512 + lane*8);
      s16x8 a1l = *reinterpret_cast<const s16x8*>(lb + pr*2048 + 1*512 + lane*8);
      s16x8 a2h = *reinterpret_cast<const s16x8*>(lb + pr*2048 + 2*512 + lane*8);
      s16x8 a2l = *reinterpret_cast<const s16x8*>(lb + pr*2048 + 3*512 + lane*8);
      s16x8 Bh = as_s16x8(bw), Bl = as_s16x8(bwl);

      // two parallel 3-deep acc chains
      f32x4 D1 = __builtin_amdgcn_mfma_f32_16x16x32_bf16(a1h, Bh, Dz, 0, 0, 0);
      f32x4 D2 = __builtin_amdgcn_mfma_f32_16x16x32_bf16(a2h, Bh, Dz, 0, 0, 0);
      D1 = __builtin_amdgcn_mfma_f32_16x16x32_bf16(a1h, Bl, D1, 0, 0, 0);
      D2 = __builtin_amdgcn_mfma_f32_16x16x32_bf16(a2h, Bl, D2, 0, 0, 0);
      D1 = __builtin_amdgcn_mfma_f32_16x16x32_bf16(a1l, Bh, D1, 0, 0, 0);
      D2 = __builtin_amdgcn_mfma_f32_16x16x32_bf16(a2l, Bh, D2, 0, 0, 0);

#pragma unroll
      for (int r = 0; r < 4; ++r) st[r] = fmaf(xb[pr], D2[r], D1[r]);

      // build next B: split, then 2 swap32 per precision
      float xs[4];
#pragma unroll
      for (int r = 0; r < 4; ++r) xs[r] = xa[pr + 1] * st[r];
      unsigned vh2[2], vl2[2], xh2[2], xl2[2];
      split4(st, vh2, vl2);
      split4(xs, xh2, xl2);
      swap32p(vh2[0], xh2[0], bw[0], bw[2]);
      swap32p(vh2[1], xh2[1], bw[1], bw[3]);
      swap32p(vl2[0], xl2[0], bwl[0], bwl[2]);
      swap32p(vl2[1], xl2[1], bwl[1], bwl[3]);
    }
    asm volatile("s_waitcnt vmcnt(0)" ::: "memory");
    __syncthreads();
    xq0 = xn0; xq1 = xn1; xq2 = xn2; xq3 = xn3;
  }

  // final f32 state (natural rows rbase..rbase+3) -> LDS
#pragma unroll
  for (int r = 0; r < 4; ++r) fin[side][q*16 + n][rbase + r] = st[r];
  __syncthreads();

  // head: y = c0 + v^T M u, 8 threads per sample (64 samples x 8 = 512 threads)
  {
    int s = tidx >> 3, j = tidx & 7;
    const float* Mf = reinterpret_cast<const float*>(ws) + 262144;
    float c0 = reinterpret_cast<const float*>(ws)[262400];
    float acc = 0.f;
#pragma unroll
    for (int dd = 0; dd < 2; ++dd) {
      int d = j*2 + dd;
      float zd = 0.f;
#pragma unroll
      for (int e = 0; e < 16; ++e) zd = fmaf(Mf[d*16 + e], fin[1][s][e], zd);
      acc = fmaf(fin[0][s][d], zd, acc);
    }
    acc += __shfl_xor(acc, 1, 64);
    acc += __shfl_xor(acc, 2, 64);
    acc += __shfl_xor(acc, 4, 64);
    if (j == 0) out[blockIdx.x*64 + s] = acc + c0;
  }
}

extern "C" void kernel_launch(void* const* d_in, const int* in_sizes, int n_in,
                              void* d_out, int out_size, void* d_ws, size_t ws_size,
                              hipStream_t stream)
{
  const float* x       = (const float*)d_in[0];
  const float* W0      = (const float*)d_in[1];
  const float* W_left  = (const float*)d_in[2];
  const float* W_out   = (const float*)d_in[3];
  const float* W_right = (const float*)d_in[4];
  const float* WN      = (const float*)d_in[5];
  const float* d1_w    = (const float*)d_in[6];
  const float* d1_b    = (const float*)d_in[7];
  const float* d2_w    = (const float*)d_in[8];
  const float* d2_b    = (const float*)d_in[9];
  unsigned short* ws   = (unsigned short*)d_ws;
  float* out           = (float*)d_out;

  if (ws_size < (size_t)WS_BYTES_NEEDED) return;

  hipLaunchKernelGGL(mps_prep, dim3(257), dim3(256), 0, stream,
                     W0, W_left, W_out, W_right, WN, d1_w, d1_b, d2_w, d2_b, ws);
  hipLaunchKernelGGL(mps_main, dim3(B_N/64), dim3(512), 0, stream,
                     x, W0, WN, ws, out);
}